// Round 7
// baseline (677.986 us; speedup 1.0000x reference)
//
#include <hip/hip_runtime.h>
#include <cstdint>
#include <cstddef>

#define BB   2
#define SEQ  4096
#define DD   768
#define HH   12
#define DHH  64
#define DFFN 3072
#define NTOK (BB*SEQ)

using bf16x8 = __attribute__((ext_vector_type(8))) __bf16;
using f32x4  = __attribute__((ext_vector_type(4))) float;
typedef unsigned int u32;

#define QK_SCALE 0.18033688011112042f   // 0.125 * log2(e): folds 1/sqrt(DH) AND e->2 base swap

__device__ __forceinline__ float fast_exp2(float x) {
    return __builtin_amdgcn_exp2f(x);   // v_exp_f32: hw computes 2^x
}

__device__ __forceinline__ unsigned short f2bf(float f) {
    unsigned u = __float_as_uint(f);
    u = u + 0x7FFFu + ((u >> 16) & 1u);
    return (unsigned short)(u >> 16);
}
// truncating bf16 (1 VALU op; rel err <2^-8, fine for P matrix)
__device__ __forceinline__ unsigned short f2bf_trunc(float f) {
    return (unsigned short)(__float_as_uint(f) >> 16);
}

__device__ __forceinline__ bf16x8 ld_bf8(const unsigned short* p) {
    return *(const bf16x8*)p;   // 16B aligned by construction
}

// async global->LDS, 16B per lane (m97 pattern)
__device__ __forceinline__ void gl_lds16(const unsigned short* g, unsigned short* l) {
    __builtin_amdgcn_global_load_lds(
        (const __attribute__((address_space(1))) u32*)(uintptr_t)(const void*)g,
        (__attribute__((address_space(3))) u32*)(uintptr_t)(void*)l,
        16, 0, 0);
}

// ---- DPP 16-lane reductions (row_ror 1/2/4/8; VALU pipe only)
template <int N>
__device__ __forceinline__ float dpp_ror(float x) {
    return __int_as_float(__builtin_amdgcn_update_dpp(
        0, __float_as_int(x), 0x120 | N, 0xf, 0xf, false));
}
__device__ __forceinline__ float rowmax16(float x) {
    x = fmaxf(x, dpp_ror<1>(x));
    x = fmaxf(x, dpp_ror<2>(x));
    x = fmaxf(x, dpp_ror<4>(x));
    x = fmaxf(x, dpp_ror<8>(x));
    return x;
}
__device__ __forceinline__ float rowsum16(float x) {
    x += dpp_ror<1>(x);
    x += dpp_ror<2>(x);
    x += dpp_ror<4>(x);
    x += dpp_ror<8>(x);
    return x;
}

// ---------------- weight prep: fp32 [R][C] -> bf16 transposed [C][R], * scale -------
__global__ __launch_bounds__(256) void transpose_f32_to_bf16(
    const float* __restrict__ src, unsigned short* __restrict__ dst, int R, int C, float scale)
{
    __shared__ float tile[32][33];
    const int c0 = blockIdx.x * 32, r0 = blockIdx.y * 32;
    const int tx = threadIdx.x, ty = threadIdx.y;   // block (32,8)
#pragma unroll
    for (int i = 0; i < 32; i += 8)
        tile[ty + i][tx] = src[(size_t)(r0 + ty + i) * C + c0 + tx];
    __syncthreads();
#pragma unroll
    for (int i = 0; i < 32; i += 8)
        dst[(size_t)(c0 + ty + i) * R + r0 + tx] = f2bf(scale * tile[tx][ty + i]);
}

__global__ void concat_bias(const float* __restrict__ bq, const float* __restrict__ bk,
                            const float* __restrict__ bv, float* __restrict__ bqkv)
{
    int i = blockIdx.x * 256 + threadIdx.x;
    if (i < 3 * DD)
        bqkv[i] = (i < DD) ? bq[i] * QK_SCALE : (i < 2 * DD ? bk[i - DD] : bv[i - 2 * DD]);
}

// ---------------- mask scan: flag=1 iff any element != 1.0f -------------------------
__global__ __launch_bounds__(256) void mask_check(const float* __restrict__ mask, int* __restrict__ flag)
{
    const size_t n = (size_t)BB * SEQ * SEQ;
    const size_t stride = (size_t)gridDim.x * 1024;
    int bad = 0;
    for (size_t i = ((size_t)blockIdx.x * 256 + threadIdx.x) * 4; i < n; i += stride) {
        float4 v = *(const float4*)&mask[i];
        bad |= (v.x != 1.f) | (v.y != 1.f) | (v.z != 1.f) | (v.w != 1.f);
    }
    if (bad) atomicOr(flag, 1);
}

// ---------------- LayerNorm (torch.std semantics: ddof=1, denom = sigma + eps) ------
__global__ __launch_bounds__(256) void ln_fused(
    const float* __restrict__ x, const float* __restrict__ add,
    const float* __restrict__ gamma, const float* __restrict__ beta,
    unsigned short* __restrict__ out_ln, float* __restrict__ x1out)
{
    const int row = blockIdx.x, t = threadIdx.x;
    const size_t base = (size_t)row * DD;
    float v[3], s = 0.f, sq = 0.f;
#pragma unroll
    for (int p = 0; p < 3; ++p) {
        int idx = t + p * 256;
        float val = x[base + idx];
        if (add) val += add[base + idx];
        v[p] = val; s += val; sq += val * val;
    }
#pragma unroll
    for (int off = 1; off < 64; off <<= 1) {
        s  += __shfl_xor(s,  off);
        sq += __shfl_xor(sq, off);
    }
    __shared__ float red[8];
    const int wave = t >> 6;
    if ((t & 63) == 0) { red[wave] = s; red[4 + wave] = sq; }
    __syncthreads();
    s  = red[0] + red[1] + red[2] + red[3];
    sq = red[4] + red[5] + red[6] + red[7];
    const float mu   = s * (1.f / 768.f);
    const float var  = fmaxf((sq - 768.f * mu * mu) * (1.f / 767.f), 0.f);
    const float rstd = 1.f / (sqrtf(var) + 1e-6f);
#pragma unroll
    for (int p = 0; p < 3; ++p) {
        int idx = t + p * 256;
        if (x1out) x1out[base + idx] = v[p];
        out_ln[base + idx] = f2bf(gamma[idx] * (v[p] - mu) * rstd + beta[idx]);
    }
}

// ---------------- bf16 GEMM v3: double-buffered LDS, 1 barrier/iter, BK=32 ----------
// stage(it+1) is issued right AFTER the barrier, consumed one iteration later:
// the vmcnt(0) drain at the next barrier waits on loads that had a full iter to land.
__global__ __launch_bounds__(256, 3) void gemm_bf16(
    const unsigned short* __restrict__ A, const unsigned short* __restrict__ Bt,
    const float* __restrict__ bias, const float* __restrict__ resid,
    unsigned short* __restrict__ outB, float* __restrict__ outF,
    int M, int N, int K, int relu)
{
    __shared__ __align__(16) unsigned short As[2][128][32];
    __shared__ __align__(16) unsigned short Bs[2][128][32];
    const int tid = threadIdx.x;
    const int lane = tid & 63, wave = tid >> 6;
    const int quad = lane >> 4, l16 = lane & 15;
    const int wm = wave >> 1, wn = wave & 1;
    const int m0 = blockIdx.y * 128, n0 = blockIdx.x * 128;

    const f32x4 fzero = {0.f, 0.f, 0.f, 0.f};
    f32x4 acc[4][4];
#pragma unroll
    for (int i = 0; i < 4; ++i)
#pragma unroll
        for (int j = 0; j < 4; ++j) acc[i][j] = fzero;

    const int r2 = tid >> 2;            // 0..63: LDS row slot (and row+64)
    const int cg = tid & 3;             // 0..3 : LDS granule slot (16B)
    // XOR swizzle: LDS slot (row, cg) holds global granule cg ^ (row&3)
    const int g0 = (cg ^ (r2 & 3)) * 8;       // same for row r2 and r2+64

    auto stage = [&](int buf, int k0) {
        gl_lds16(&A [(size_t)(m0 + r2) * K + k0 + g0],       &As[buf][r2][cg * 8]);
        gl_lds16(&A [(size_t)(m0 + 64 + r2) * K + k0 + g0],  &As[buf][64 + r2][cg * 8]);
        gl_lds16(&Bt[(size_t)(n0 + r2) * K + k0 + g0],       &Bs[buf][r2][cg * 8]);
        gl_lds16(&Bt[(size_t)(n0 + 64 + r2) * K + k0 + g0],  &Bs[buf][64 + r2][cg * 8]);
    };

    const int gsw = (quad ^ (l16 & 3)) * 8;   // frag-read un-permute (row&3 == l16&3)
    const int iters = K >> 5;
    stage(0, 0);
    for (int it = 0; it < iters; ++it) {
        __syncthreads();                       // drains stage(it) (full iter in flight) + prev ds reads
        if (it + 1 < iters) stage((it + 1) & 1, (it + 1) * 32);
        const int buf = it & 1;
        bf16x8 af[4], bfv[4];
#pragma unroll
        for (int i = 0; i < 4; ++i) af[i]  = ld_bf8(&As[buf][wm * 64 + i * 16 + l16][gsw]);
#pragma unroll
        for (int j = 0; j < 4; ++j) bfv[j] = ld_bf8(&Bs[buf][wn * 64 + j * 16 + l16][gsw]);
#pragma unroll
        for (int i = 0; i < 4; ++i)
#pragma unroll
            for (int j = 0; j < 4; ++j)
                acc[i][j] = __builtin_amdgcn_mfma_f32_16x16x32_bf16(af[i], bfv[j], acc[i][j], 0, 0, 0);
    }
#pragma unroll
    for (int i = 0; i < 4; ++i)
#pragma unroll
        for (int j = 0; j < 4; ++j)
#pragma unroll
            for (int rr = 0; rr < 4; ++rr) {
                const int gm = m0 + wm * 64 + i * 16 + quad * 4 + rr;
                const int gn = n0 + wn * 64 + j * 16 + l16;
                float v = acc[i][j][rr] + bias[gn];
                if (relu) v = fmaxf(v, 0.f);
                if (resid) v += resid[(size_t)gm * N + gn];
                if (outF) outF[(size_t)gm * N + gn] = v;
                if (outB) outB[(size_t)gm * N + gn] = f2bf(v);
            }
}

// ---------------- V^T extraction: qkv V-cols -> vtg[bh][64][4096] -------------------
__global__ __launch_bounds__(256) void vt_extract(
    const unsigned short* __restrict__ qkv, unsigned short* __restrict__ vtg)
{
    __shared__ unsigned short tile[64][72];
    const int bh = blockIdx.x, b = bh / HH, h = bh % HH;
    const int s0 = blockIdx.y * 64;
    const int tid = threadIdx.x;
#pragma unroll
    for (int p = 0; p < 2; ++p) {
        int idx = tid + p * 256;
        int r = idx >> 3, ch8 = (idx & 7) * 8;
        *(uint4*)&tile[r][ch8] =
            *(const uint4*)&qkv[(size_t)(b * SEQ + s0 + r) * 2304 + 1536 + h * 64 + ch8];
    }
    __syncthreads();
#pragma unroll
    for (int p = 0; p < 2; ++p) {
        int idx = tid + p * 256;
        int d = idx >> 3, sc = (idx & 7) * 8;
        unsigned short tmp[8];
#pragma unroll
        for (int j = 0; j < 8; ++j) tmp[j] = tile[sc + j][d];
        *(uint4*)&vtg[((size_t)bh * 64 + d) * SEQ + s0 + sc] = *(uint4*)tmp;
    }
}

// ---------------- flash attention v6: 52 KB LDS -> 3 blocks/CU, per-mt Ps -----------
// grid = (SEQ/128, BB*HH) = 768 blocks = exactly 3/CU x 256 CUs (one full round).
__global__ __launch_bounds__(256, 3) void flash_attn6(
    const unsigned short* __restrict__ qkv, const unsigned short* __restrict__ vtg,
    const float* __restrict__ mask, const int* __restrict__ maskflag,
    float* __restrict__ ctx)
{
    __shared__ __align__(16) unsigned short Ks[128][72];    // stride 36 dw == 4 mod 32
    __shared__ __align__(16) unsigned short Vt[64][136];    // stride 68 dw == 4 mod 32
    __shared__ __align__(16) unsigned short Ps[4][16][136]; // per-wave, reused across mt
    const int tid = threadIdx.x;
    const int lane = tid & 63, wave = tid >> 6;
    const int quad = lane >> 4, l16 = lane & 15;
    const int bh = blockIdx.y, b = bh / HH, h = bh % HH;
    const int qbase = blockIdx.x * 128 + wave * 32;
    const int use_mask = *maskflag;

    bf16x8 qf[2][2];
#pragma unroll
    for (int mt = 0; mt < 2; ++mt) {
        const size_t qrow = (size_t)(b * SEQ + qbase + mt * 16 + l16) * 2304 + h * 64;
        qf[mt][0] = ld_bf8(&qkv[qrow + quad * 8]);
        qf[mt][1] = ld_bf8(&qkv[qrow + 32 + quad * 8]);
    }
    const f32x4 fzero = {0.f, 0.f, 0.f, 0.f};
    float l_run[2][4];
    f32x4 o[2][4];
#pragma unroll
    for (int mt = 0; mt < 2; ++mt)
#pragma unroll
        for (int r = 0; r < 4; ++r) { l_run[mt][r] = 0.f; o[mt][r] = fzero; }

    const float* mbase = mask + (size_t)b * SEQ * SEQ;
    const unsigned short* kgbase = qkv + (size_t)b * SEQ * 2304 + 768 + h * 64;
    const unsigned short* vgbase = vtg + (size_t)bh * 64 * SEQ;

    if (!use_mask) {
        // ======================= FAST PATH (mask == all-ones) =======================
        float lsum[2][4];
#pragma unroll
        for (int mt = 0; mt < 2; ++mt)
#pragma unroll
            for (int r = 0; r < 4; ++r) lsum[mt][r] = 0.f;

        for (int k0 = 0; k0 < SEQ; k0 += 128) {
            __syncthreads();
#pragma unroll
            for (int p = 0; p < 4; ++p) {
                int idx = tid + p * 256;
                int row = idx >> 3, ch8 = (idx & 7) * 8;
                *(uint4*)&Ks[row][ch8] = *(const uint4*)&kgbase[(size_t)(k0 + row) * 2304 + ch8];
            }
#pragma unroll
            for (int p = 0; p < 4; ++p) {
                int idx = tid + p * 256;
                int d = idx >> 4, ch8 = (idx & 15) * 8;
                *(uint4*)&Vt[d][ch8] = *(const uint4*)&vgbase[(size_t)d * SEQ + k0 + ch8];
            }
            __syncthreads();

            f32x4 st[2][8];
#pragma unroll
            for (int j = 0; j < 8; ++j) {
                bf16x8 kf0 = ld_bf8(&Ks[j * 16 + l16][quad * 8]);
                bf16x8 kf1 = ld_bf8(&Ks[j * 16 + l16][32 + quad * 8]);
                st[0][j] = __builtin_amdgcn_mfma_f32_16x16x32_bf16(qf[0][0], kf0, fzero, 0, 0, 0);
                st[0][j] = __builtin_amdgcn_mfma_f32_16x16x32_bf16(qf[0][1], kf1, st[0][j], 0, 0, 0);
                st[1][j] = __builtin_amdgcn_mfma_f32_16x16x32_bf16(qf[1][0], kf0, fzero, 0, 0, 0);
                st[1][j] = __builtin_amdgcn_mfma_f32_16x16x32_bf16(qf[1][1], kf1, st[1][j], 0, 0, 0);
            }
#pragma unroll
            for (int mt = 0; mt < 2; ++mt) {
                // p = exp2(s); defer row reduction: per-lane partial sums only
#pragma unroll
                for (int r = 0; r < 4; ++r) {
                    float acc = 0.f;
#pragma unroll
                    for (int j = 0; j < 8; ++j) {
                        float p = fast_exp2(st[mt][j][r]);
                        st[mt][j][r] = p;
                        acc += p;
                    }
                    lsum[mt][r] += acc;
                }
                // P (C-layout) -> per-wave LDS -> A-layout; in-order DS within wave
#pragma unroll
                for (int j = 0; j < 8; ++j)
#pragma unroll
                    for (int r = 0; r < 4; ++r)
                        Ps[wave][quad * 4 + r][j * 16 + l16] = f2bf_trunc(st[mt][j][r]);
#pragma unroll
                for (int kk = 0; kk < 4; ++kk) {
                    bf16x8 pf = ld_bf8(&Ps[wave][l16][kk * 32 + quad * 8]);
#pragma unroll
                    for (int t = 0; t < 4; ++t) {
                        bf16x8 vf = ld_bf8(&Vt[t * 16 + l16][kk * 32 + quad * 8]);
                        o[mt][t] = __builtin_amdgcn_mfma_f32_16x16x32_bf16(pf, vf, o[mt][t], 0, 0, 0);
                    }
                }
            }
        }
#pragma unroll
        for (int mt = 0; mt < 2; ++mt)
#pragma unroll
            for (int r = 0; r < 4; ++r) l_run[mt][r] = rowsum16(lsum[mt][r]);
    } else {
        // ======================= GENERAL PATH (arbitrary mult. mask) ================
        float m_run[2][4];
#pragma unroll
        for (int mt = 0; mt < 2; ++mt)
#pragma unroll
            for (int r = 0; r < 4; ++r) m_run[mt][r] = -1e30f;

        for (int k0 = 0; k0 < SEQ; k0 += 128) {
            __syncthreads();
#pragma unroll
            for (int p = 0; p < 4; ++p) {
                int idx = tid + p * 256;
                int row = idx >> 3, ch8 = (idx & 7) * 8;
                *(uint4*)&Ks[row][ch8] = *(const uint4*)&kgbase[(size_t)(k0 + row) * 2304 + ch8];
            }
#pragma unroll
            for (int p = 0; p < 4; ++p) {
                int idx = tid + p * 256;
                int d = idx >> 4, ch8 = (idx & 15) * 8;
                *(uint4*)&Vt[d][ch8] = *(const uint4*)&vgbase[(size_t)d * SEQ + k0 + ch8];
            }
            __syncthreads();

            f32x4 st[2][8];
#pragma unroll
            for (int j = 0; j < 8; ++j) {
                bf16x8 kf0 = ld_bf8(&Ks[j * 16 + l16][quad * 8]);
                bf16x8 kf1 = ld_bf8(&Ks[j * 16 + l16][32 + quad * 8]);
                st[0][j] = __builtin_amdgcn_mfma_f32_16x16x32_bf16(qf[0][0], kf0, fzero, 0, 0, 0);
                st[0][j] = __builtin_amdgcn_mfma_f32_16x16x32_bf16(qf[0][1], kf1, st[0][j], 0, 0, 0);
                st[1][j] = __builtin_amdgcn_mfma_f32_16x16x32_bf16(qf[1][0], kf0, fzero, 0, 0, 0);
                st[1][j] = __builtin_amdgcn_mfma_f32_16x16x32_bf16(qf[1][1], kf1, st[1][j], 0, 0, 0);
            }
#pragma unroll
            for (int mt = 0; mt < 2; ++mt) {
                const int qr = qbase + mt * 16 + quad * 4;
#pragma unroll
                for (int r = 0; r < 4; ++r) {
                    const float* mrow = &mbase[(size_t)(qr + r) * SEQ + k0 + l16];
#pragma unroll
                    for (int j = 0; j < 8; ++j)
                        st[mt][j][r] *= mrow[j * 16];
                }
                float alpha[4];
#pragma unroll
                for (int r = 0; r < 4; ++r) {
                    float mx = st[mt][0][r];
#pragma unroll
                    for (int j = 1; j < 8; ++j) mx = fmaxf(mx, st[mt][j][r]);
                    mx = rowmax16(mx);
                    const float mnew = fmaxf(m_run[mt][r], mx);
                    alpha[r] = fast_exp2(m_run[mt][r] - mnew);
                    float ssum = 0.f;
#pragma unroll
                    for (int j = 0; j < 8; ++j) {
                        st[mt][j][r] = fast_exp2(st[mt][j][r] - mnew);
                        ssum += st[mt][j][r];
                    }
                    ssum = rowsum16(ssum);
                    l_run[mt][r] = l_run[mt][r] * alpha[r] + ssum;
                    m_run[mt][r] = mnew;
                }
#pragma unroll
                for (int t = 0; t < 4; ++t)
#pragma unroll
                    for (int r = 0; r < 4; ++r) o[mt][t][r] *= alpha[r];
#pragma unroll
                for (int j = 0; j < 8; ++j)
#pragma unroll
                    for (int r = 0; r < 4; ++r)
                        Ps[wave][quad * 4 + r][j * 16 + l16] = f2bf_trunc(st[mt][j][r]);
#pragma unroll
                for (int kk = 0; kk < 4; ++kk) {
                    bf16x8 pf = ld_bf8(&Ps[wave][l16][kk * 32 + quad * 8]);
#pragma unroll
                    for (int t = 0; t < 4; ++t) {
                        bf16x8 vf = ld_bf8(&Vt[t * 16 + l16][kk * 32 + quad * 8]);
                        o[mt][t] = __builtin_amdgcn_mfma_f32_16x16x32_bf16(pf, vf, o[mt][t], 0, 0, 0);
                    }
                }
            }
        }
    }

#pragma unroll
    for (int mt = 0; mt < 2; ++mt)
#pragma unroll
        for (int r = 0; r < 4; ++r) {
            const float inv = 1.f / l_run[mt][r];
            const int row = qbase + mt * 16 + quad * 4 + r;
#pragma unroll
            for (int t = 0; t < 4; ++t)
                ctx[(size_t)(b * SEQ + row) * DD + h * 64 + t * 16 + l16] = o[mt][t][r] * inv;
        }
}

// -----------------------------------------------------------------------------------
extern "C" void kernel_launch(void* const* d_in, const int* in_sizes, int n_in,
                              void* d_out, int out_size, void* d_ws, size_t ws_size,
                              hipStream_t stream)
{
    (void)in_sizes; (void)n_in; (void)out_size; (void)ws_size;
    const float* x      = (const float*)d_in[0];
    const float* mask   = (const float*)d_in[1];
    const float* wq     = (const float*)d_in[2];
    const float* bq     = (const float*)d_in[3];
    const float* wk     = (const float*)d_in[4];
    const float* bk     = (const float*)d_in[5];
    const float* wv     = (const float*)d_in[6];
    const float* bv     = (const float*)d_in[7];
    // d_in[8]=wo, d_in[9]=bo: reference never applies out_linear — intentionally unused
    const float* w1     = (const float*)d_in[10];
    const float* b1     = (const float*)d_in[11];
    const float* w2     = (const float*)d_in[12];
    const float* b2     = (const float*)d_in[13];
    const float* gamma1 = (const float*)d_in[14];
    const float* beta1  = (const float*)d_in[15];
    const float* gamma2 = (const float*)d_in[16];
    const float* beta2  = (const float*)d_in[17];
    float* out = (float*)d_out;

    char* ws = (char*)d_ws;
    size_t off = 0;
    auto take = [&](size_t bytes) -> char* {
        char* p = ws + off;
        off = (off + bytes + 255) & ~(size_t)255;
        return p;
    };
    unsigned short* wqkvT = (unsigned short*)take((size_t)2304 * 768 * 2);
    unsigned short* w1T   = (unsigned short*)take((size_t)3072 * 768 * 2);
    unsigned short* w2T   = (unsigned short*)take((size_t)768 * 3072 * 2);
    float*          bqkv  = (float*)take(2304 * 4);
    int*            mflag = (int*)take(256);
    unsigned short* l12   = (unsigned short*)take((size_t)NTOK * DD * 2);
    unsigned short* qkv   = (unsigned short*)take((size_t)NTOK * 2304 * 2);
    float*          x1    = (float*)take((size_t)NTOK * DD * 4);
    // big region (50.3 MB): during attention = [ctx 25.2 MB | vtg 25.2 MB]; later hb.
    char*           big   = take((size_t)NTOK * DFFN * 2);
    float*          ctx   = (float*)big;
    unsigned short* vtg   = (unsigned short*)(big + (size_t)NTOK * DD * 4);
    unsigned short* hb    = (unsigned short*)big;

    (void)hipMemsetAsync(mflag, 0, 4, stream);
    mask_check<<<2048, 256, 0, stream>>>(mask, mflag);

    // weight prep (QK_SCALE = 0.125*log2e folded into wq/bq -> scores in log2 domain)
    transpose_f32_to_bf16<<<dim3(24, 24), dim3(32, 8), 0, stream>>>(wq, wqkvT,                 768, 768, QK_SCALE);
    transpose_f32_to_bf16<<<dim3(24, 24), dim3(32, 8), 0, stream>>>(wk, wqkvT + 768 * 768,     768, 768, 1.0f);
    transpose_f32_to_bf16<<<dim3(24, 24), dim3(32, 8), 0, stream>>>(wv, wqkvT + 2 * 768 * 768, 768, 768, 1.0f);
    transpose_f32_to_bf16<<<dim3(96, 24), dim3(32, 8), 0, stream>>>(w1, w1T,                   768, 3072, 1.0f);
    transpose_f32_to_bf16<<<dim3(24, 96), dim3(32, 8), 0, stream>>>(w2, w2T,                   3072, 768, 1.0f);
    concat_bias<<<9, 256, 0, stream>>>(bq, bk, bv, bqkv);

    // LN1 -> l1 (bf16)
    ln_fused<<<NTOK, 256, 0, stream>>>(x, nullptr, gamma1, beta1, l12, nullptr);
    // fused QKV GEMM
    gemm_bf16<<<dim3(2304 / 128, NTOK / 128), 256, 0, stream>>>(
        l12, wqkvT, bqkv, nullptr, qkv, nullptr, NTOK, 2304, 768, 0);
    // V^T per head
    vt_extract<<<dim3(BB * HH, SEQ / 64), 256, 0, stream>>>(qkv, vtg);
    // flash attention v6 -> ctx fp32
    flash_attn6<<<dim3(SEQ / 128, BB * HH), 256, 0, stream>>>(qkv, vtg, mask, mflag, ctx);
    // x1 = x + ctx, LN2 -> l2 (bf16)
    ln_fused<<<NTOK, 256, 0, stream>>>(x, ctx, gamma2, beta2, l12, x1);
    // FFN1: relu(l2 @ w1 + b1) -> hb
    gemm_bf16<<<dim3(3072 / 128, NTOK / 128), 256, 0, stream>>>(
        l12, w1T, b1, nullptr, hb, nullptr, NTOK, 3072, 768, 1);
    // FFN2: hb @ w2 + b2 + x1 -> out
    gemm_bf16<<<dim3(768 / 128, NTOK / 128), 256, 0, stream>>>(
        hb, w2T, b2, x1, nullptr, out, NTOK, 768, 3072, 0);
}